// Round 4
// baseline (5616.023 us; speedup 1.0000x reference)
//
#include <hip/hip_runtime.h>
#include <hip/hip_bf16.h>
#include <math.h>

typedef __hip_bfloat16 bf16;

__device__ __forceinline__ float b2f(bf16 v){ return __bfloat162float(v); }
__device__ __forceinline__ bf16  f2b(float v){ return __float2bfloat16(v); }

// residual row address in the split d_out layout:
// token t in concat space (w = t/65, r = t%65): r<16 -> out_ct slot (w*16+r),
// else out_x row (w*49 + r-16). split==0: contiguous ct rows (carrier path).
__device__ __forceinline__ float* row_addr(float* ct, float* x, int t, int split)
{
    if (!split) return ct + (size_t)t * 128;
    int w = t / 65, r = t - w * 65;
    if (r < 16) return ct + ((size_t)w * 16 + r) * 128;
    return x + ((size_t)w * 49 + (r - 16)) * 128;
}

// ---------------- posemb MLP: out[seq][128] = relu(t@w1+b1)@w2 (fp32) ----------------
__global__ void posemb_kernel(const float* __restrict__ w1, const float* __restrict__ b1,
                              const float* __restrict__ w2, float* __restrict__ out, int s)
{
    int i = blockIdx.x;
    int c = threadIdx.x;
    int half = s / 2;
    float t0 = (float)(i / s - half) / (float)half;
    float t1 = (float)(i % s - half) / (float)half;
    float acc = 0.f;
    for (int k = 0; k < 512; k++){
        float h = t0 * w1[k] + t1 * w1[512 + k] + b1[k];
        h = fmaxf(h, 0.f);
        acc += h * w2[k * 128 + c];
    }
    out[i * 128 + c] = acc;
}

// ------------- CPB table: tbl[(2ws-1)^2][4] = 16*sigmoid(relu(t@w1+b1)@w2) -------------
__global__ void cpb_kernel(const float* __restrict__ w1, const float* __restrict__ b1,
                           const float* __restrict__ w2, float* __restrict__ tbl, int ws)
{
    int d = 2 * ws - 1;
    int ne = d * d;
    int e = blockIdx.x * 64 + threadIdx.x;
    if (e >= ne) return;
    float rh = (float)(e / d - (ws - 1));
    float rw = (float)(e % d - (ws - 1));
    float t0 = rh / (float)(ws - 1) * 8.f;
    float t1 = rw / (float)(ws - 1) * 8.f;
    float s0 = (t0 > 0.f) ? 1.f : ((t0 < 0.f) ? -1.f : 0.f);
    float s1 = (t1 > 0.f) ? 1.f : ((t1 < 0.f) ? -1.f : 0.f);
    t0 = s0 * log2f(fabsf(t0) + 1.f) * (1.f / 3.f);
    t1 = s1 * log2f(fabsf(t1) + 1.f) * (1.f / 3.f);
    float acc[4] = {0.f, 0.f, 0.f, 0.f};
    for (int k = 0; k < 512; k++){
        float h = t0 * w1[k] + t1 * w1[512 + k] + b1[k];
        h = fmaxf(h, 0.f);
        #pragma unroll
        for (int hh = 0; hh < 4; hh++) acc[hh] += h * w2[k * 4 + hh];
    }
    #pragma unroll
    for (int hh = 0; hh < 4; hh++)
        tbl[e * 4 + hh] = 16.f / (1.f + expf(-acc[hh]));
}

// ---------------- ct_init: out_ct = ct + hpe ----------------
__global__ void ct_init_kernel(const float* __restrict__ ct, const float* __restrict__ hpe,
                               float* __restrict__ out_ct)
{
    int idx = blockIdx.x * 256 + threadIdx.x;      // over 65536*128
    out_ct[idx] = ct[idx] + hpe[idx % (256 * 128)];
}

// ---------------- x_init: out_x = x_in + pe ----------------
__global__ void x_init_kernel(const float* __restrict__ x_in, const float* __restrict__ pe,
                              float* __restrict__ out_x)
{
    int idx = blockIdx.x * 256 + threadIdx.x;      // over 4096*49*128
    out_x[idx] = x_in[idx] + pe[idx % (49 * 128)];
}

// ---------------- LayerNorm (128ch), 4 tokens/block, float in/out ----------------
__global__ __launch_bounds__(256) void ln_kernel(const float* __restrict__ src,
    const float* __restrict__ g, const float* __restrict__ b, float* __restrict__ out)
{
    int m = blockIdx.x * 4 + (threadIdx.x >> 6);
    int lane = threadIdx.x & 63;
    const float* row = src + (size_t)m * 128;
    float v0 = row[lane], v1 = row[lane + 64];
    float s = v0 + v1, s2 = v0 * v0 + v1 * v1;
    #pragma unroll
    for (int off = 32; off >= 1; off >>= 1){
        s  += __shfl_xor(s,  off, 64);
        s2 += __shfl_xor(s2, off, 64);
    }
    float mean = s * (1.f / 128.f);
    float var  = s2 * (1.f / 128.f) - mean * mean;
    float r = rsqrtf(var + 1e-5f);
    float* o = out + (size_t)m * 128;
    o[lane]      = (v0 - mean) * r * g[lane]      + b[lane];
    o[lane + 64] = (v1 - mean) * r * g[lane + 64] + b[lane + 64];
}

// ---------------- GEMM: 8 tokens x 128 cols per block ----------------
// mode 0: out = A@W (+bias)   mode 2: ACC += gamma*(A@W+bias), N==128
__global__ __launch_bounds__(128) void gemm_kernel(
    const float* __restrict__ A, const float* __restrict__ W,
    const float* __restrict__ bias, const float* __restrict__ gamma,
    float* ACC, float* __restrict__ out, int K, int N, int mode)
{
    int m0 = blockIdx.x * 8;
    int n  = blockIdx.y * 128 + threadIdx.x;
    float acc[8] = {0.f,0.f,0.f,0.f,0.f,0.f,0.f,0.f};
    for (int k = 0; k < K; k++){
        float w = W[(size_t)k * N + n];
        #pragma unroll
        for (int t = 0; t < 8; t++)
            acc[t] += A[(size_t)(m0 + t) * K + k] * w;
    }
    float bv = bias ? bias[n] : 0.f;
    if (mode == 2){
        float gv = gamma[n];
        #pragma unroll
        for (int t = 0; t < 8; t++){
            float* p = ACC + (size_t)(m0 + t) * 128 + n;
            *p = *p + gv * (acc[t] + bv);
        }
    } else {
        #pragma unroll
        for (int t = 0; t < 8; t++)
            out[(size_t)(m0 + t) * N + n] = acc[t] + bv;
    }
}

// ---------------- carrier attention (N=256), qkv precomputed (float) ----------------
__global__ __launch_bounds__(256) void attn_kernel(
    const float* __restrict__ qkv, const float* __restrict__ btbl,
    float* __restrict__ out)
{
    __shared__ bf16  Ks[256 * 32];
    __shared__ bf16  Vs[256 * 32];
    __shared__ float Ss[16 * 256];
    __shared__ float Qs[16 * 32];
    __shared__ float rowsum[16];

    int bx  = blockIdx.x;
    int ch  = bx & 15;           // 16 chunks of 16 rows
    int h   = (bx >> 4) & 3;
    int b   = bx >> 6;
    int tid = threadIdx.x;
    int r0  = ch * 16;
    const float scale = 0.17677669529663688f;   // 1/sqrt(32)

    for (int idx = tid; idx < 256 * 32; idx += 256){
        int j = idx >> 5, dd = idx & 31;
        size_t base = (size_t)(b * 256 + j) * 384 + h * 32 + dd;
        Ks[idx] = f2b(qkv[base + 128]);
        Vs[idx] = f2b(qkv[base + 256]);
    }
    for (int idx = tid; idx < 16 * 32; idx += 256){
        int ri = idx >> 5, dd = idx & 31;
        Qs[idx] = qkv[(size_t)(b * 256 + r0 + ri) * 384 + h * 32 + dd];
    }
    __syncthreads();

    for (int ri = 0; ri < 16; ri++){
        int row = r0 + ri;
        for (int j = tid; j < 256; j += 256){
            float acc = 0.f;
            #pragma unroll
            for (int dd = 0; dd < 32; dd++)
                acc += Qs[ri * 32 + dd] * b2f(Ks[j * 32 + dd]);
            acc *= scale;
            int di = (row >> 4) - (j >> 4) + 15;
            int dj = (row & 15) - (j & 15) + 15;
            acc += btbl[(di * 31 + dj) * 4 + h];
            Ss[ri * 256 + j] = acc;
        }
    }
    __syncthreads();

    {
        int ri = tid >> 4, c = tid & 15;
        float m = -1e30f;
        for (int j = c; j < 256; j += 16) m = fmaxf(m, Ss[ri * 256 + j]);
        #pragma unroll
        for (int off = 1; off < 16; off <<= 1) m = fmaxf(m, __shfl_xor(m, off, 16));
        float l = 0.f;
        for (int j = c; j < 256; j += 16){
            float p = expf(Ss[ri * 256 + j] - m);
            Ss[ri * 256 + j] = p;
            l += p;
        }
        #pragma unroll
        for (int off = 1; off < 16; off <<= 1) l += __shfl_xor(l, off, 16);
        if (c == 0) rowsum[ri] = l;
    }
    __syncthreads();

    for (int idx = tid; idx < 16 * 32; idx += 256){
        int ri = idx >> 5, dd = idx & 31;
        float acc = 0.f;
        for (int j = 0; j < 256; j++)
            acc += Ss[ri * 256 + j] * b2f(Vs[j * 32 + dd]);
        acc /= rowsum[ri];
        out[(size_t)(b * 256 + r0 + ri) * 128 + h * 32 + dd] = acc;
    }
}

// ---------------- fused main-path window attention + proj + gamma3 residual ----------------
// one block per window (65 tokens), residual lives in d_out (split layout)
__global__ __launch_bounds__(256) void win_attn_fused(
    float* ct_res, float* x_res,
    const float* __restrict__ Wqkv,  // [128][384]
    const float* __restrict__ g, const float* __restrict__ bta,
    const float* __restrict__ btbl,  // [169][4]
    const float* __restrict__ Wp, const float* __restrict__ bp,
    const float* __restrict__ g3)
{
    __shared__ bf16  Xs[65][128];
    __shared__ bf16  Qs[65][32];
    __shared__ bf16  Ks2[65][32];
    __shared__ bf16  Vs2[65][32];
    __shared__ bf16  Ao[65][128];
    __shared__ float Ss[65][66];
    __shared__ float linv[65];

    int w = blockIdx.x, tid = threadIdx.x;

    // LN into Xs (bf16 tiles, fp32 math)
    int wv = tid >> 6, lane = tid & 63;
    for (int t = wv; t < 65; t += 4){
        const float* row = row_addr(ct_res, x_res, w * 65 + t, 1);
        float v0 = row[lane], v1 = row[lane + 64];
        float s = v0 + v1, s2 = v0 * v0 + v1 * v1;
        #pragma unroll
        for (int off = 32; off >= 1; off >>= 1){
            s  += __shfl_xor(s,  off, 64);
            s2 += __shfl_xor(s2, off, 64);
        }
        float mean = s * (1.f / 128.f);
        float var  = s2 * (1.f / 128.f) - mean * mean;
        float r = rsqrtf(var + 1e-5f);
        Xs[t][lane]      = f2b((v0 - mean) * r * g[lane]      + bta[lane]);
        Xs[t][lane + 64] = f2b((v1 - mean) * r * g[lane + 64] + bta[lane + 64]);
    }
    __syncthreads();

    for (int h = 0; h < 4; h++){
        // qkv for head h
        int dd = tid & 31, tg = tid >> 5;
        for (int c = 0; c < 2; c++){
            int t0 = c * 64 + tg * 8;
            if (t0 < 65){
                float aq[8], ak[8], av[8];
                #pragma unroll
                for (int i = 0; i < 8; i++){ aq[i] = ak[i] = av[i] = 0.f; }
                const bf16* xr[8];
                #pragma unroll
                for (int i = 0; i < 8; i++){ int t = t0 + i; xr[i] = Xs[t < 65 ? t : 64]; }
                for (int k = 0; k < 128; k++){
                    float wq  = Wqkv[k * 384 +       h * 32 + dd];
                    float wk  = Wqkv[k * 384 + 128 + h * 32 + dd];
                    float wvv = Wqkv[k * 384 + 256 + h * 32 + dd];
                    #pragma unroll
                    for (int i = 0; i < 8; i++){
                        float xv = b2f(xr[i][k]);
                        aq[i] += xv * wq; ak[i] += xv * wk; av[i] += xv * wvv;
                    }
                }
                #pragma unroll
                for (int i = 0; i < 8; i++){
                    int t = t0 + i;
                    if (t < 65){ Qs[t][dd] = f2b(aq[i]); Ks2[t][dd] = f2b(ak[i]); Vs2[t][dd] = f2b(av[i]); }
                }
            }
        }
        __syncthreads();

        // scores + bias
        for (int e = tid; e < 65 * 65; e += 256){
            int i = e / 65, j = e - i * 65;
            float acc = 0.f;
            #pragma unroll
            for (int d2 = 0; d2 < 32; d2++)
                acc += b2f(Qs[i][d2]) * b2f(Ks2[j][d2]);
            acc *= 0.17677669529663688f;
            if (i >= 16 && j >= 16){
                int wp = i - 16, wq2 = j - 16;
                int di = wp / 7 - wq2 / 7 + 6;
                int dj = wp % 7 - wq2 % 7 + 6;
                acc += btbl[(di * 13 + dj) * 4 + h];
            }
            Ss[i][j] = acc;
        }
        __syncthreads();

        // softmax (one thread per row)
        if (tid < 65){
            float m = -1e30f;
            for (int j = 0; j < 65; j++) m = fmaxf(m, Ss[tid][j]);
            float l = 0.f;
            for (int j = 0; j < 65; j++){
                float p = expf(Ss[tid][j] - m);
                Ss[tid][j] = p; l += p;
            }
            linv[tid] = 1.f / l;
        }
        __syncthreads();

        // P @ V -> Ao channels of this head
        for (int e = tid; e < 65 * 32; e += 256){
            int i = e >> 5, d2 = e & 31;
            float acc = 0.f;
            for (int j = 0; j < 65; j++)
                acc += Ss[i][j] * b2f(Vs2[j][d2]);
            Ao[i][h * 32 + d2] = f2b(acc * linv[i]);
        }
        __syncthreads();
    }

    // proj + gamma3 residual update
    {
        int n = tid & 127, tg = tid >> 7;
        float gv = g3[n], bv = bp[n];
        for (int r = tg; r < 65; r += 2){
            float acc = 0.f;
            for (int c = 0; c < 128; c++)
                acc += b2f(Ao[r][c]) * Wp[c * 128 + n];
            acc += bv;
            float* p = row_addr(ct_res, x_res, w * 65 + r, 1) + n;
            *p = *p + gv * acc;
        }
    }
}

// ---------------- fused LN + MLP (+gamma residual), 16 tokens/block ----------------
__global__ __launch_bounds__(256) void mlp_fused(
    float* ct_res, float* x_res, int split,
    const float* __restrict__ g,  const float* __restrict__ b,
    const float* __restrict__ W1, const float* __restrict__ b1,
    const float* __restrict__ W2, const float* __restrict__ b2,
    const float* __restrict__ gamma)
{
    __shared__ bf16  Xb[16][128];
    __shared__ float H[16][512];
    int m0 = blockIdx.x * 16;
    int tid = threadIdx.x;

    int wv = tid >> 6, lane = tid & 63;
    for (int t = wv; t < 16; t += 4){
        const float* row = row_addr(ct_res, x_res, m0 + t, split);
        float v0 = row[lane], v1 = row[lane + 64];
        float s = v0 + v1, s2 = v0 * v0 + v1 * v1;
        #pragma unroll
        for (int off = 32; off >= 1; off >>= 1){
            s  += __shfl_xor(s,  off, 64);
            s2 += __shfl_xor(s2, off, 64);
        }
        float mean = s * (1.f / 128.f);
        float var  = s2 * (1.f / 128.f) - mean * mean;
        float r = rsqrtf(var + 1e-5f);
        Xb[t][lane]      = f2b((v0 - mean) * r * g[lane]      + b[lane]);
        Xb[t][lane + 64] = f2b((v1 - mean) * r * g[lane + 64] + b[lane + 64]);
    }
    __syncthreads();

    // H = gelu(Xb @ W1 + b1)
    for (int k = tid; k < 512; k += 256){
        float acc[16];
        #pragma unroll
        for (int t = 0; t < 16; t++) acc[t] = 0.f;
        for (int c = 0; c < 128; c++){
            float w1v = W1[c * 512 + k];
            #pragma unroll
            for (int t = 0; t < 16; t++) acc[t] += b2f(Xb[t][c]) * w1v;
        }
        float bb = b1[k];
        #pragma unroll
        for (int t = 0; t < 16; t++){
            float x = acc[t] + bb;
            H[t][k] = 0.5f * x * (1.f + erff(x * 0.70710678118654752f));
        }
    }
    __syncthreads();

    // residual += gamma * (H @ W2 + b2)
    int n = tid & 127, tg = tid >> 7;
    float acc[8];
    #pragma unroll
    for (int i = 0; i < 8; i++) acc[i] = 0.f;
    for (int k = 0; k < 512; k++){
        float w2v = W2[k * 128 + n];
        #pragma unroll
        for (int i = 0; i < 8; i++) acc[i] += H[tg * 8 + i][k] * w2v;
    }
    float bb = b2[n], gv = gamma[n];
    #pragma unroll
    for (int i = 0; i < 8; i++){
        float* p = row_addr(ct_res, x_res, m0 + tg * 8 + i, split) + n;
        *p = *p + gv * (acc[i] + bb);
    }
}

// ---------------- final x: out_x += gamma1 * upsampled carrier (in place) ----------------
__global__ void final_x_kernel(float* out_x, const float* __restrict__ out_ct,
                               const float* __restrict__ g1)
{
    int idx = blockIdx.x * 256 + threadIdx.x;   // over 4096*49*128
    int w   = idx / (49 * 128);
    int rem = idx % (49 * 128);
    int p   = rem >> 7;
    int c   = rem & 127;
    int a = p / 7, bc = p % 7;
    int s = ((a * 4) / 7) * 4 + (bc * 4) / 7;
    out_x[idx] = out_x[idx] + g1[c] * out_ct[((size_t)w * 16 + s) * 128 + c];
}

extern "C" void kernel_launch(void* const* d_in, const int* in_sizes, int n_in,
                              void* d_out, int out_size, void* d_ws, size_t ws_size,
                              hipStream_t stream)
{
    const float* x_in        = (const float*)d_in[0];
    const float* ct_in       = (const float*)d_in[1];
    const float* pe_w1       = (const float*)d_in[2];
    const float* pe_b1       = (const float*)d_in[3];
    const float* pe_w2       = (const float*)d_in[4];
    const float* hpe_w1      = (const float*)d_in[5];
    const float* hpe_b1      = (const float*)d_in[6];
    const float* hpe_w2      = (const float*)d_in[7];
    const float* n1_g        = (const float*)d_in[8];
    const float* n1_b        = (const float*)d_in[9];
    const float* n2_g        = (const float*)d_in[10];
    const float* n2_b        = (const float*)d_in[11];
    const float* hn1_g       = (const float*)d_in[12];
    const float* hn1_b       = (const float*)d_in[13];
    const float* hn2_g       = (const float*)d_in[14];
    const float* hn2_b       = (const float*)d_in[15];
    const float* attn_qkv_w  = (const float*)d_in[16];
    const float* attn_proj_w = (const float*)d_in[17];
    const float* attn_proj_b = (const float*)d_in[18];
    const float* attn_cpb_w1 = (const float*)d_in[19];
    const float* attn_cpb_b1 = (const float*)d_in[20];
    const float* attn_cpb_w2 = (const float*)d_in[21];
    const float* hat_qkv_w   = (const float*)d_in[22];
    const float* hat_proj_w  = (const float*)d_in[23];
    const float* hat_proj_b  = (const float*)d_in[24];
    const float* hat_cpb_w1  = (const float*)d_in[25];
    const float* hat_cpb_b1  = (const float*)d_in[26];
    const float* hat_cpb_w2  = (const float*)d_in[27];
    const float* mlp_w1      = (const float*)d_in[28];
    const float* mlp_b1      = (const float*)d_in[29];
    const float* mlp_w2      = (const float*)d_in[30];
    const float* mlp_b2      = (const float*)d_in[31];
    const float* hmlp_w1     = (const float*)d_in[32];
    const float* hmlp_b1     = (const float*)d_in[33];
    const float* hmlp_w2     = (const float*)d_in[34];
    const float* hmlp_b2     = (const float*)d_in[35];
    const float* gamma1      = (const float*)d_in[36];
    const float* gamma2      = (const float*)d_in[37];
    const float* gamma3      = (const float*)d_in[38];
    const float* gamma4      = (const float*)d_in[39];

    const int M2 = 4096 * 65;   // 266240 concat tokens
    const int MC = 256 * 256;   // 65536 carrier tokens

    // residuals live in d_out (float). carrier qkv scratch (65536*384*4 =
    // 100.7MB) borrows the then-dead out_x region (4096*49*128*4 = 102.8MB).
    float* out_x  = (float*)d_out;                        // [4096*49][128]
    float* out_ct = out_x + (size_t)4096 * 49 * 128;      // [65536][128] carrier residual
    float* qkvC   = out_x;

    // workspace: one 33.6MB timeshared buffer + small tables (~34 MB total)
    char* p = (char*)d_ws;
    float* S     = (float*)p; p += (size_t)MC * 128 * 4;  // LN-out then attn-out (carrier)
    float* pe    = (float*)p; p += 49 * 128 * 4;
    float* hpe   = (float*)p; p += 256 * 128 * 4;
    float* btbl7 = (float*)p; p += 169 * 4 * 4;
    float* btbl16= (float*)p; p += 961 * 4 * 4;

    posemb_kernel<<<49, 128, 0, stream>>>(pe_w1, pe_b1, pe_w2, pe, 7);
    posemb_kernel<<<256, 128, 0, stream>>>(hpe_w1, hpe_b1, hpe_w2, hpe, 16);
    cpb_kernel<<<3, 64, 0, stream>>>(attn_cpb_w1, attn_cpb_b1, attn_cpb_w2, btbl7, 7);
    cpb_kernel<<<16, 64, 0, stream>>>(hat_cpb_w1, hat_cpb_b1, hat_cpb_w2, btbl16, 16);

    // ---- carrier path (residual = out_ct) ----
    ct_init_kernel<<<(MC * 128) / 256, 256, 0, stream>>>(ct_in, hpe, out_ct);
    ln_kernel<<<MC / 4, 256, 0, stream>>>(out_ct, hn1_g, hn1_b, S);
    gemm_kernel<<<dim3(MC / 8, 3), 128, 0, stream>>>(S, hat_qkv_w, nullptr, nullptr,
                                                     nullptr, qkvC, 128, 384, 0);
    attn_kernel<<<256 * 4 * 16, 256, 0, stream>>>(qkvC, btbl16, S);
    gemm_kernel<<<dim3(MC / 8, 1), 128, 0, stream>>>(S, hat_proj_w, hat_proj_b, gamma1,
                                                     out_ct, nullptr, 128, 128, 2);
    mlp_fused<<<MC / 16, 256, 0, stream>>>(out_ct, nullptr, 0, hn2_g, hn2_b,
                                           hmlp_w1, hmlp_b1, hmlp_w2, hmlp_b2, gamma2);

    // ---- main path (residual = out_x + out_ct slots, split layout) ----
    x_init_kernel<<<(4096 * 49 * 128) / 256, 256, 0, stream>>>(x_in, pe, out_x);
    win_attn_fused<<<4096, 256, 0, stream>>>(out_ct, out_x, attn_qkv_w, n1_g, n1_b,
                                             btbl7, attn_proj_w, attn_proj_b, gamma3);
    mlp_fused<<<M2 / 16, 256, 0, stream>>>(out_ct, out_x, 1, n2_g, n2_b,
                                           mlp_w1, mlp_b1, mlp_w2, mlp_b2, gamma4);

    // ---- finalize (out_ct already holds final carrier residual) ----
    final_x_kernel<<<(4096 * 49 * 128) / 256, 256, 0, stream>>>(out_x, out_ct, gamma1);
}